// Round 11
// baseline (299.174 us; speedup 1.0000x reference)
//
#include <hip/hip_runtime.h>
#include <stdint.h>

#define N_KEYS 200000
#define N_Q    1024
#define DIM    128
#define KNN    50
#define DELTA  1e-3f

#define NKP     200064                 // 1563 * 128 padded keys
#define TILES64 3126                   // NKP / 64
#define NSTRIP  96
#define STRIP_R 54                     // 3126 = 54*33 + 42*32
#define SAMPLES 2048
#define NSTILE  16                     // 16 sample tiles x 128 keys
#define STILE_STRIDE 97                // 128-key tile idx = s*97 (max 1455 < 1563)
#define SAMPLE_RANK 8
#define CAP2    3072
#define SEG     20                     // per (strip,query) candidate slots (Poisson mean ~8.4)
#define OVFCAP  65536
#define BANDW   0.125f                 // sure/band split half-width (>= 2*e_fp16)
#define TSLACK  0.25f                  // tau filter slack for fp16 approx error

typedef __attribute__((ext_vector_type(8))) _Float16 f16x8;
typedef __attribute__((ext_vector_type(4))) float f32x4;
typedef unsigned long long ull;

#define GLD16(gsrc, ldst) __builtin_amdgcn_global_load_lds( \
    (const __attribute__((address_space(1))) unsigned int*)(gsrc), \
    (__attribute__((address_space(3))) unsigned int*)(ldst), 16, 0, 0)
#define GLD4(gsrc, ldst) __builtin_amdgcn_global_load_lds( \
    (const __attribute__((address_space(1))) unsigned int*)(gsrc), \
    (__attribute__((address_space(3))) unsigned int*)(ldst), 4, 0, 0)

// ================================================================ prep: fp32 -> f16 fragment-tiled + row sq-sums
__global__ void prep_kernel(const float* __restrict__ qry, const float* __restrict__ keys,
                            ushort* __restrict__ Kf, ushort* __restrict__ Qf,
                            float* __restrict__ ksq, float* __restrict__ qsq,
                            unsigned int* __restrict__ ovf_cnt) {
    if (blockIdx.x == 0 && threadIdx.x == 0) *ovf_cnt = 0u;
    const int wave = threadIdx.x >> 6, lane = threadIdx.x & 63;
    const long NKG = NKP / 16;              // 12504
    const long NQG = N_Q / 16;              // 64
    const long grp = (long)blockIdx.x * 4 + wave;
    if (grp >= NKG + NQG) return;
    const bool isq = (grp >= NKG);
    const long lgrp = isq ? (grp - NKG) : grp;
    const long row = lgrp * 16 + (lane & 15);
    const int  hi  = lane >> 4;
    const bool valid = isq || (row < N_KEYS);
    const float* src = isq ? (qry + row * DIM) : (keys + (valid ? row * DIM : 0));

    float ss = 0.f;
    uint4 hv[4];
    #pragma unroll
    for (int s = 0; s < 4; ++s) {
        float4 a, b;
        if (valid) {
            const float4* p = (const float4*)(src + s * 32 + hi * 8);
            a = p[0]; b = p[1];
        } else {
            a = make_float4(0.f, 0.f, 0.f, 0.f); b = a;
        }
        ss = fmaf(a.x, a.x, ss); ss = fmaf(a.y, a.y, ss);
        ss = fmaf(a.z, a.z, ss); ss = fmaf(a.w, a.w, ss);
        ss = fmaf(b.x, b.x, ss); ss = fmaf(b.y, b.y, ss);
        ss = fmaf(b.z, b.z, ss); ss = fmaf(b.w, b.w, ss);
        const float v[8] = {a.x, a.y, a.z, a.w, b.x, b.y, b.z, b.w};
        unsigned h[8];
        #pragma unroll
        for (int j = 0; j < 8; ++j) {
            _Float16 t = (_Float16)v[j];
            h[j] = (unsigned)__builtin_bit_cast(unsigned short, t);
        }
        hv[s].x = h[0] | (h[1] << 16); hv[s].y = h[2] | (h[3] << 16);
        hv[s].z = h[4] | (h[5] << 16); hv[s].w = h[6] | (h[7] << 16);
    }
    ss += __shfl_xor(ss, 16);
    ss += __shfl_xor(ss, 32);

    ushort* dst = isq ? Qf : Kf;
    #pragma unroll
    for (int s = 0; s < 4; ++s)
        *(uint4*)(dst + (size_t)(lgrp * 4 + s) * 512 + lane * 8) = hv[s];

    if (lane < 16) {
        if (isq) qsq[row] = ss;
        else if (row < NKP) ksq[row] = valid ? ss : 3.0e38f;
    }
}

// ================================================================ tau phase A: MFMA approx distances for 16 sampled tiles
__global__ __launch_bounds__(256)
void tau_dist_kernel(const ushort* __restrict__ Qf, const ushort* __restrict__ Kf,
                     const float* __restrict__ ksq_g, const float* __restrict__ qsq_g,
                     float* __restrict__ Ds) {
    __shared__ ushort Blds[16384];
    const int qt = blockIdx.x >> 4;
    const int st = blockIdx.x & 15;
    const int ktile = st * STILE_STRIDE;
    const int qbase = qt * 128, kbase = ktile * 128;
    const int tid = threadIdx.x, lane = tid & 63, wave = tid >> 6;
    const int wr = wave >> 1, wc = wave & 1;
    const int col = lane & 15, rowb = (lane >> 4) * 4;

    {
        const ushort* src = Kf + (size_t)ktile * 16384 + lane * 8;
        #pragma unroll
        for (int c = 0; c < 8; ++c)
            GLD16(src + (wave * 8 + c) * 512, &Blds[(wave * 8 + c) * 512]);
    }
    f16x8 af[4][4];
    {
        const ushort* qsrc = Qf + (size_t)qt * 16384 + lane * 8;
        #pragma unroll
        for (int i = 0; i < 4; ++i)
            #pragma unroll
            for (int s = 0; s < 4; ++s)
                af[i][s] = *(const f16x8*)(qsrc + ((wr * 4 + i) * 4 + s) * 512);
    }
    float qsq_r[4][4];
    #pragma unroll
    for (int i = 0; i < 4; ++i)
        #pragma unroll
        for (int r = 0; r < 4; ++r)
            qsq_r[i][r] = qsq_g[qbase + wr * 64 + i * 16 + rowb + r];
    float ksq4[4];
    #pragma unroll
    for (int j = 0; j < 4; ++j)
        ksq4[j] = ksq_g[kbase + wc * 64 + j * 16 + col];
    __syncthreads();

    f32x4 acc[4][4];
    #pragma unroll
    for (int i = 0; i < 4; ++i)
        #pragma unroll
        for (int j = 0; j < 4; ++j) acc[i][j] = (f32x4){0.f, 0.f, 0.f, 0.f};
    #pragma unroll
    for (int s = 0; s < 4; ++s) {
        f16x8 bfr[4];
        #pragma unroll
        for (int j = 0; j < 4; ++j)
            bfr[j] = *(const f16x8*)&Blds[((wc * 4 + j) * 4 + s) * 512 + lane * 8];
        #pragma unroll
        for (int i = 0; i < 4; ++i)
            #pragma unroll
            for (int j = 0; j < 4; ++j)
                acc[i][j] = __builtin_amdgcn_mfma_f32_16x16x32_f16(af[i][s], bfr[j], acc[i][j], 0, 0, 0);
    }

    #pragma unroll
    for (int i = 0; i < 4; ++i) {
        #pragma unroll
        for (int j = 0; j < 4; ++j) {
            #pragma unroll
            for (int r = 0; r < 4; ++r) {
                const int ql = wr * 64 + i * 16 + rowb + r;
                const int kl = wc * 64 + j * 16 + col;
                const float dist = qsq_r[i][r] + fmaf(-2.f, acc[i][j][r], ksq4[j]);
                Ds[(size_t)(qbase + ql) * SAMPLES + st * 128 + kl] = dist;
            }
        }
    }
}

// ================================================================ tau phase B: per-query rank-8 radix select (4 q/block)
__global__ __launch_bounds__(256)
void tau_select_kernel(const float* __restrict__ Ds, float* __restrict__ tau0, int rank) {
    __shared__ float D[4][SAMPLES];     // 32 KB
    const int q0 = blockIdx.x * 4, tid = threadIdx.x;
    {
        const float4* srcv = (const float4*)(Ds + (size_t)q0 * SAMPLES);
        float4* dstv = (float4*)&D[0][0];
        for (int i = tid; i < SAMPLES; i += 256) dstv[i] = srcv[i];
    }
    __syncthreads();

    const int wave = tid >> 6, lane = tid & 63;
    const float* Dq = D[wave];
    unsigned int v = 0;
    for (int bit = 30; bit >= 0; bit--) {
        const unsigned int tbits = v | (1u << bit);
        const float tf = __uint_as_float(tbits);
        unsigned int lc = 0;
        for (int i = lane; i < SAMPLES; i += 64) lc += (Dq[i] < tf) ? 1u : 0u;
        #pragma unroll
        for (int m = 1; m < 64; m <<= 1) lc += __shfl_xor(lc, m);
        if (lc < (unsigned)rank) v = tbits;
    }
    if (lane == 0) tau0[q0 + wave] = __uint_as_float(v);
}

// ================================================================ f16 MFMA distance GEMM + filter
// 64-key tiles; barrier at LOOP HEAD (drains only aged loads), stage issued
// AFTER the barrier so prefetch stays in flight across compute+epilogue.
__global__ __launch_bounds__(256, 3)
void mfma_filter_kernel(const ushort* __restrict__ Qf, const ushort* __restrict__ Kf,
                        const float* __restrict__ ksq_g, const float* __restrict__ qsq_g,
                        const float* __restrict__ tau_g,
                        uint2* __restrict__ cand2, unsigned int* __restrict__ cnt2,
                        uint2* __restrict__ ovf, unsigned int* __restrict__ ovf_cnt) {
    __shared__ ushort Blds[2][8192];      // 2 x 16 KB K-tile double buffer
    __shared__ uint2 hitbuf[128][SEG];    // 20 KB block-local hits (mm_bits, kg)
    __shared__ float ksqs[2][64];         // staged ksq per tile
    __shared__ unsigned int lcnt[128];    // per-query hit counts

    const int wg = blockIdx.x;
    const int qt = wg / NSTRIP;
    const int strip = wg - qt * NSTRIP;   // 96%8==0 -> wg%8 == strip%8 -> same XCD for all 8 qt
    int t0, len;
    if (strip < STRIP_R) { t0 = strip * 33; len = 33; }
    else { t0 = STRIP_R * 33 + (strip - STRIP_R) * 32; len = 32; }

    const int qbase = qt * 128;
    const int tid = threadIdx.x, lane = tid & 63, wave = tid >> 6;
    const int wr = wave >> 1, wc = wave & 1;   // wave covers 64q x 32k
    const int col = lane & 15, rowb = (lane >> 4) * 4;

    // Q fragments -> registers
    f16x8 af[4][4];
    {
        const ushort* qsrc = Qf + (size_t)qt * 16384 + lane * 8;
        #pragma unroll
        for (int i = 0; i < 4; ++i)
            #pragma unroll
            for (int s = 0; s < 4; ++s)
                af[i][s] = *(const f16x8*)(qsrc + ((wr * 4 + i) * 4 + s) * 512);
    }
    // per-lane thresholds only (qsq added at write-out)
    float thr_r[4][4];
    #pragma unroll
    for (int i = 0; i < 4; ++i)
        #pragma unroll
        for (int r = 0; r < 4; ++r) {
            const int qg = qbase + wr * 64 + i * 16 + rowb + r;
            thr_r[i][r] = tau_g[qg] + TSLACK - qsq_g[qg];
        }

    if (tid < 128) lcnt[tid] = 0u;
    {   // prologue: issue stage of tile t0 -> buf 0 (drained by first loop-head barrier)
        const ushort* src = Kf + (size_t)t0 * 8192 + lane * 8;
        #pragma unroll
        for (int c = 0; c < 4; ++c)
            GLD16(src + (wave * 4 + c) * 512, &Blds[0][(wave * 4 + c) * 512]);
        if (wave == 0) GLD4(ksq_g + (size_t)t0 * 64 + lane, &ksqs[0][0]);
    }

    for (int t = 0; t < len; ++t) {
        const int kt = t0 + t;
        const int cur = t & 1;

        // barrier FIRST: drains tile-t loads (issued >=1 tile ago, already landed)
        // and releases buf cur^1 for the next stage.
        __syncthreads();

        // issue next-tile stage AFTER the barrier -> stays in flight across compute
        if (t + 1 < len) {
            const ushort* src = Kf + (size_t)(kt + 1) * 8192 + lane * 8;
            #pragma unroll
            for (int c = 0; c < 4; ++c)
                GLD16(src + (wave * 4 + c) * 512, &Blds[cur ^ 1][(wave * 4 + c) * 512]);
            if (wave == 0) GLD4(ksq_g + (size_t)(kt + 1) * 64 + lane, &ksqs[cur ^ 1][0]);
        }

        float ksq2[2];
        ksq2[0] = ksqs[cur][wc * 32 + col];
        ksq2[1] = ksqs[cur][wc * 32 + 16 + col];

        f32x4 acc[4][2];
        #pragma unroll
        for (int i = 0; i < 4; ++i)
            #pragma unroll
            for (int j = 0; j < 2; ++j) acc[i][j] = (f32x4){0.f, 0.f, 0.f, 0.f};

        #pragma unroll
        for (int s = 0; s < 4; ++s) {
            f16x8 bfr[2];
            #pragma unroll
            for (int j = 0; j < 2; ++j)
                bfr[j] = *(const f16x8*)&Blds[cur][((wc * 2 + j) * 4 + s) * 512 + lane * 8];
            #pragma unroll
            for (int i = 0; i < 4; ++i)
                #pragma unroll
                for (int j = 0; j < 2; ++j)
                    acc[i][j] = __builtin_amdgcn_mfma_f32_16x16x32_f16(af[i][s], bfr[j], acc[i][j], 0, 0, 0);
        }

        // epilogue: LDS-only hit append (no global traffic in the loop)
        #pragma unroll
        for (int i = 0; i < 4; ++i) {
            #pragma unroll
            for (int j = 0; j < 2; ++j) {
                #pragma unroll
                for (int r = 0; r < 4; ++r) {
                    const float mm = fmaf(-2.f, acc[i][j][r], ksq2[j]);
                    if (mm < thr_r[i][r]) {
                        const int ql = wr * 64 + i * 16 + rowb + r;
                        const unsigned kg = (unsigned)(kt * 64 + wc * 32 + j * 16 + col);
                        const unsigned slot = atomicAdd(&lcnt[ql], 1u);
                        if (slot < (unsigned)SEG) {
                            hitbuf[ql][slot] = make_uint2(__float_as_uint(mm), kg);
                        } else {   // rare overflow -> global list (dist computed here)
                            const int qg = qbase + ql;
                            const float dist = qsq_g[qg] + mm;
                            const unsigned op = atomicAdd(ovf_cnt, 1u);
                            if (op < (unsigned)OVFCAP)
                                ovf[op] = make_uint2(__float_as_uint(dist),
                                                     ((unsigned)qg << 18) | kg);
                        }
                    }
                }
            }
        }
    }
    __syncthreads();   // all epilogue hits visible before write-out

    // coalesced write-out: 2 threads per query
    {
        const int ql = tid >> 1, sub = tid & 1;
        const unsigned n = min(lcnt[ql], (unsigned)SEG);
        const float qsq = qsq_g[qbase + ql];
        uint2* seg = cand2 + ((size_t)strip * N_Q + qbase + ql) * SEG;
        for (unsigned i = sub; i < n; i += 2) {
            const uint2 e = hitbuf[ql][i];
            seg[i] = make_uint2(__float_as_uint(qsq + __uint_as_float(e.x)), e.y);
        }
        if (sub == 0) cnt2[(size_t)strip * N_Q + qbase + ql] = n;
    }
}

// ================================================================ select: gather -> radix a50 -> band-only exact recompute -> IDW
__global__ __launch_bounds__(256)
void select_kernel(const uint2* __restrict__ cand2, const unsigned int* __restrict__ cnt2,
                   const uint2* __restrict__ ovf, const unsigned int* __restrict__ ovf_cnt,
                   const float* __restrict__ keys, const float* __restrict__ qry,
                   const float* __restrict__ ksq_g, const float* __restrict__ qsq_g,
                   const float* __restrict__ values, float* __restrict__ out) {
    __shared__ float Qs[DIM];
    __shared__ unsigned dbits[CAP2];
    __shared__ unsigned didx[CAP2];
    __shared__ unsigned band_idx[128];
    __shared__ ull bandkey[128];
    __shared__ ull sel[64];
    __shared__ float vv[64];
    __shared__ unsigned int ns_sure, nb, galloc, a50_s;
    const int q = blockIdx.x, tid = threadIdx.x;

    if (tid < 32) ((float4*)Qs)[tid] = ((const float4*)(qry + (size_t)q * DIM))[tid];
    if (tid == 0) { ns_sure = 0; nb = 0; galloc = 0; }
    __syncthreads();

    // gather 96 segments: 2 threads/strip, LDS-atomic allocation (order-independent use)
    {
        const int s = tid >> 1, sub = tid & 1;
        if (s < NSTRIP) {
            const unsigned n = cnt2[(size_t)s * N_Q + q];
            unsigned base = 0;
            if (sub == 0) base = atomicAdd(&galloc, n);
            base = __shfl(base, (tid & 63) & ~1);
            const uint2* seg = cand2 + ((size_t)s * N_Q + q) * SEG;
            for (unsigned i = sub; i < n; i += 2) {
                const unsigned dsti = base + i;
                if (dsti < (unsigned)CAP2) {
                    const uint2 e = seg[i];
                    dbits[dsti] = e.x; didx[dsti] = e.y;
                }
            }
        }
    }
    // rare overflow entries
    {
        const unsigned no = min(*ovf_cnt, (unsigned)OVFCAP);
        for (unsigned i = tid; i < no; i += 256) {
            const uint2 e = ovf[i];
            if ((e.y >> 18) == (unsigned)q) {
                const unsigned dsti = atomicAdd(&galloc, 1u);
                if (dsti < (unsigned)CAP2) { dbits[dsti] = e.x; didx[dsti] = e.y & 0x3FFFFu; }
            }
        }
    }
    __syncthreads();
    const int c = min((int)galloc, CAP2);
    const int ksel = min(KNN, c);
    if (ksel == 0) { if (tid == 0) out[q] = 0.f; return; }

    // ---- radix select a50 = ksel-th smallest approx dist (wave-redundant, barrier-free)
    const int lane = tid & 63;
    {
        unsigned v = 0;
        for (int bit = 30; bit >= 0; bit--) {
            const unsigned tb = v | (1u << bit);
            unsigned lc = 0;
            for (int i = lane; i < c; i += 64) lc += (dbits[i] < tb) ? 1u : 0u;
            #pragma unroll
            for (int m = 1; m < 64; m <<= 1) lc += __shfl_xor(lc, m);
            if (lc < (unsigned)ksel) v = tb;
        }
        if (tid == 0) a50_s = v;
    }
    __syncthreads();
    const float a50 = __uint_as_float(a50_s);
    const float lo_cut = a50 - BANDW, hi_cut = a50 + BANDW;

    // ---- classify: sure (approx) / band (needs exact)
    for (int i = tid; i < c; i += 256) {
        const float A = __uint_as_float(dbits[i]);
        if (A < lo_cut) {
            const unsigned p = atomicAdd(&ns_sure, 1u);
            if (p < 64u) sel[p] = ((ull)dbits[i] << 32) | didx[i];
        } else if (A <= hi_cut) {
            const unsigned p = atomicAdd(&nb, 1u);
            if (p < 128u) band_idx[p] = didx[i];
        }
    }
    __syncthreads();
    const int nsure = min((int)ns_sure, 64);
    const int nband = min((int)nb, 128);
    const int need = min(ksel - nsure, nband);

    // ---- exact fp32 recompute for band (4 threads / element)
    const float qsq = qsq_g[q];
    for (int base = 0; base < nband; base += 64) {
        const int j = base + (tid >> 2);
        if (j < nband) {
            const int part = tid & 3;
            const int kidx = (int)band_idx[j];
            const float* kr = keys + (size_t)kidx * DIM + part * 32;
            const float* qp = Qs + part * 32;
            float acc = 0.f;
            #pragma unroll
            for (int d4 = 0; d4 < 8; ++d4) {
                const float4 kv = ((const float4*)kr)[d4];
                const float4 qv = ((const float4*)qp)[d4];
                acc = fmaf(qv.x, kv.x, acc); acc = fmaf(qv.y, kv.y, acc);
                acc = fmaf(qv.z, kv.z, acc); acc = fmaf(qv.w, kv.w, acc);
            }
            acc += __shfl_xor(acc, 1);
            acc += __shfl_xor(acc, 2);
            if (part == 0) {
                const float mm = fmaf(-2.f, acc, ksq_g[kidx]);
                const float dist = qsq + mm;
                bandkey[j] = ((ull)__float_as_uint(dist) << 32) | (unsigned)kidx;
            }
        }
    }
    __syncthreads();

    // ---- rank-place best `need` band elements (deterministic slots)
    if (tid < nband) {
        const ull mykey = bandkey[tid];
        int rank = 0;
        for (int i = 0; i < nband; ++i) rank += (bandkey[i] < mykey) ? 1 : 0;
        if (rank < need) sel[nsure + rank] = mykey;
    }
    __syncthreads();
    const int nfinal = nsure + max(need, 0);

    if (tid == 0) {  // deterministic order: insertion sort ascending (dist, idx)
        for (int a = 1; a < nfinal; a++) {
            const ull xk = sel[a];
            int b = a - 1;
            while (b >= 0 && sel[b] > xk) { sel[b + 1] = sel[b]; b--; }
            sel[b + 1] = xk;
        }
    }
    __syncthreads();
    if (tid < nfinal) vv[tid] = values[(unsigned)(sel[tid] & 0xFFFFFFFFull)];
    __syncthreads();

    if (tid == 0) {
        const float d0 = fmaxf(__uint_as_float((unsigned)(sel[0] >> 32)), 0.f);
        float res;
        if (d0 == 0.f) {
            res = vv[0];
        } else {
            float S = 0.f;
            for (int i = 0; i < nfinal; i++) {
                const float di = fmaxf(__uint_as_float((unsigned)(sel[i] >> 32)), 0.f);
                S += 1.f / (di + DELTA);
            }
            float o = 0.f;
            for (int i = 0; i < nfinal; i++) {
                const float di = fmaxf(__uint_as_float((unsigned)(sel[i] >> 32)), 0.f);
                const float w = 1.f / (di + DELTA);
                o += (w / S) * vv[i];
            }
            res = o;
        }
        out[q] = res;
    }
}

// ================================================================ launcher
extern "C" void kernel_launch(void* const* d_in, const int* in_sizes, int n_in,
                              void* d_out, int out_size, void* d_ws, size_t ws_size,
                              hipStream_t stream) {
    const float* qry    = (const float*)d_in[0];   // [1024,128]
    const float* keys   = (const float*)d_in[1];   // [200000,128]
    const float* values = (const float*)d_in[2];   // [200000,1]
    float* out = (float*)d_out;
    char* ws = (char*)d_ws;

    const size_t KF_OFF   = 0;
    const size_t QF_OFF   = KF_OFF  + (size_t)NKP * DIM * 2;     // 51,216,384
    const size_t KSQ_OFF  = QF_OFF  + (size_t)N_Q * DIM * 2;     // +262,144
    const size_t QSQ_OFF  = KSQ_OFF + (size_t)NKP * 4;           // +800,256
    const size_t TAU_OFF  = QSQ_OFF + 4096;
    const size_t OVFC_OFF = TAU_OFF + 4096;
    const size_t OVF_OFF  = OVFC_OFF + 4096;
    const size_t CNT2_OFF = OVF_OFF + (size_t)OVFCAP * 8;        // +512 KB
    const size_t CAND2_OFF= CNT2_OFF + (size_t)NSTRIP * N_Q * 4; // +384 KB
    // cand2: 96*1024*20*8 = 15.7 MB. Ds (8 MB) aliases cand2 (disjoint liveness).

    ushort* Kf  = (ushort*)(ws + KF_OFF);
    ushort* Qf  = (ushort*)(ws + QF_OFF);
    float*  ksq = (float*)(ws + KSQ_OFF);
    float*  qsq = (float*)(ws + QSQ_OFF);
    float*  tau = (float*)(ws + TAU_OFF);
    unsigned int* ovf_cnt = (unsigned int*)(ws + OVFC_OFF);
    uint2*  ovf  = (uint2*)(ws + OVF_OFF);
    unsigned int* cnt2 = (unsigned int*)(ws + CNT2_OFF);
    uint2*  cand2 = (uint2*)(ws + CAND2_OFF);
    float*  Ds   = (float*)(ws + CAND2_OFF);

    const int PREP_BLOCKS = (int)((NKP / 16 + N_Q / 16 + 3) / 4);   // 3142

    hipLaunchKernelGGL(prep_kernel, dim3(PREP_BLOCKS), dim3(256), 0, stream,
                       qry, keys, Kf, Qf, ksq, qsq, ovf_cnt);
    hipLaunchKernelGGL(tau_dist_kernel, dim3(8 * NSTILE), dim3(256), 0, stream,
                       Qf, Kf, ksq, qsq, Ds);
    hipLaunchKernelGGL(tau_select_kernel, dim3(N_Q / 4), dim3(256), 0, stream,
                       Ds, tau, SAMPLE_RANK);
    hipLaunchKernelGGL(mfma_filter_kernel, dim3(8 * NSTRIP), dim3(256), 0, stream,
                       Qf, Kf, ksq, qsq, tau, cand2, cnt2, ovf, ovf_cnt);
    hipLaunchKernelGGL(select_kernel, dim3(N_Q), dim3(256), 0, stream,
                       cand2, cnt2, ovf, ovf_cnt, keys, qry, ksq, qsq, values, out);
}

// Round 12
// 271.141 us; speedup vs baseline: 1.1034x; 1.1034x over previous
//
#include <hip/hip_runtime.h>
#include <stdint.h>

#define N_KEYS 200000
#define N_Q    1024
#define DIM    128
#define KNN    50
#define DELTA  1e-3f

#define NKP     200064                 // 1563 * 128 padded keys
#define TILES64 3126                   // NKP / 64
#define NSTRIP  96
#define STRIP_R 54                     // 3126 = 54*33 + 42*32
#define SAMPLES 2048
#define NSTILE  16                     // 16 sample tiles x 128 keys
#define STILE_STRIDE 97                // 128-key tile idx = s*97 (max 1455 < 1563)
#define SAMPLE_RANK 8
#define CAP2    3072
#define SEG     20                     // per (strip,query) candidate slots (Poisson mean ~8.4)
#define OVFCAP  65536
#define BANDW   0.125f                 // sure/band split half-width (>= 2*e_fp16)
#define TSLACK  0.25f                  // tau filter slack for fp16 approx error

typedef __attribute__((ext_vector_type(8))) _Float16 f16x8;
typedef __attribute__((ext_vector_type(4))) float f32x4;
typedef unsigned long long ull;

#define GLD16(gsrc, ldst) __builtin_amdgcn_global_load_lds( \
    (const __attribute__((address_space(1))) unsigned int*)(gsrc), \
    (__attribute__((address_space(3))) unsigned int*)(ldst), 16, 0, 0)

// ================================================================ prep: fp32 -> f16 fragment-tiled + row sq-sums
__global__ void prep_kernel(const float* __restrict__ qry, const float* __restrict__ keys,
                            ushort* __restrict__ Kf, ushort* __restrict__ Qf,
                            float* __restrict__ ksq, float* __restrict__ qsq,
                            unsigned int* __restrict__ ovf_cnt) {
    if (blockIdx.x == 0 && threadIdx.x == 0) *ovf_cnt = 0u;
    const int wave = threadIdx.x >> 6, lane = threadIdx.x & 63;
    const long NKG = NKP / 16;              // 12504
    const long NQG = N_Q / 16;              // 64
    const long grp = (long)blockIdx.x * 4 + wave;
    if (grp >= NKG + NQG) return;
    const bool isq = (grp >= NKG);
    const long lgrp = isq ? (grp - NKG) : grp;
    const long row = lgrp * 16 + (lane & 15);
    const int  hi  = lane >> 4;
    const bool valid = isq || (row < N_KEYS);
    const float* src = isq ? (qry + row * DIM) : (keys + (valid ? row * DIM : 0));

    float ss = 0.f;
    uint4 hv[4];
    #pragma unroll
    for (int s = 0; s < 4; ++s) {
        float4 a, b;
        if (valid) {
            const float4* p = (const float4*)(src + s * 32 + hi * 8);
            a = p[0]; b = p[1];
        } else {
            a = make_float4(0.f, 0.f, 0.f, 0.f); b = a;
        }
        ss = fmaf(a.x, a.x, ss); ss = fmaf(a.y, a.y, ss);
        ss = fmaf(a.z, a.z, ss); ss = fmaf(a.w, a.w, ss);
        ss = fmaf(b.x, b.x, ss); ss = fmaf(b.y, b.y, ss);
        ss = fmaf(b.z, b.z, ss); ss = fmaf(b.w, b.w, ss);
        const float v[8] = {a.x, a.y, a.z, a.w, b.x, b.y, b.z, b.w};
        unsigned h[8];
        #pragma unroll
        for (int j = 0; j < 8; ++j) {
            _Float16 t = (_Float16)v[j];
            h[j] = (unsigned)__builtin_bit_cast(unsigned short, t);
        }
        hv[s].x = h[0] | (h[1] << 16); hv[s].y = h[2] | (h[3] << 16);
        hv[s].z = h[4] | (h[5] << 16); hv[s].w = h[6] | (h[7] << 16);
    }
    ss += __shfl_xor(ss, 16);
    ss += __shfl_xor(ss, 32);

    ushort* dst = isq ? Qf : Kf;
    #pragma unroll
    for (int s = 0; s < 4; ++s)
        *(uint4*)(dst + (size_t)(lgrp * 4 + s) * 512 + lane * 8) = hv[s];

    if (lane < 16) {
        if (isq) qsq[row] = ss;
        else if (row < NKP) ksq[row] = valid ? ss : 3.0e38f;
    }
}

// ================================================================ tau phase A: MFMA approx distances for 16 sampled tiles
__global__ __launch_bounds__(256)
void tau_dist_kernel(const ushort* __restrict__ Qf, const ushort* __restrict__ Kf,
                     const float* __restrict__ ksq_g, const float* __restrict__ qsq_g,
                     float* __restrict__ Ds) {
    __shared__ ushort Blds[16384];
    const int qt = blockIdx.x >> 4;
    const int st = blockIdx.x & 15;
    const int ktile = st * STILE_STRIDE;
    const int qbase = qt * 128, kbase = ktile * 128;
    const int tid = threadIdx.x, lane = tid & 63, wave = tid >> 6;
    const int wr = wave >> 1, wc = wave & 1;
    const int col = lane & 15, rowb = (lane >> 4) * 4;

    {
        const ushort* src = Kf + (size_t)ktile * 16384 + lane * 8;
        #pragma unroll
        for (int c = 0; c < 8; ++c)
            GLD16(src + (wave * 8 + c) * 512, &Blds[(wave * 8 + c) * 512]);
    }
    f16x8 af[4][4];
    {
        const ushort* qsrc = Qf + (size_t)qt * 16384 + lane * 8;
        #pragma unroll
        for (int i = 0; i < 4; ++i)
            #pragma unroll
            for (int s = 0; s < 4; ++s)
                af[i][s] = *(const f16x8*)(qsrc + ((wr * 4 + i) * 4 + s) * 512);
    }
    float qsq_r[4][4];
    #pragma unroll
    for (int i = 0; i < 4; ++i)
        #pragma unroll
        for (int r = 0; r < 4; ++r)
            qsq_r[i][r] = qsq_g[qbase + wr * 64 + i * 16 + rowb + r];
    float ksq4[4];
    #pragma unroll
    for (int j = 0; j < 4; ++j)
        ksq4[j] = ksq_g[kbase + wc * 64 + j * 16 + col];
    __syncthreads();

    f32x4 acc[4][4];
    #pragma unroll
    for (int i = 0; i < 4; ++i)
        #pragma unroll
        for (int j = 0; j < 4; ++j) acc[i][j] = (f32x4){0.f, 0.f, 0.f, 0.f};
    #pragma unroll
    for (int s = 0; s < 4; ++s) {
        f16x8 bfr[4];
        #pragma unroll
        for (int j = 0; j < 4; ++j)
            bfr[j] = *(const f16x8*)&Blds[((wc * 4 + j) * 4 + s) * 512 + lane * 8];
        #pragma unroll
        for (int i = 0; i < 4; ++i)
            #pragma unroll
            for (int j = 0; j < 4; ++j)
                acc[i][j] = __builtin_amdgcn_mfma_f32_16x16x32_f16(af[i][s], bfr[j], acc[i][j], 0, 0, 0);
    }

    #pragma unroll
    for (int i = 0; i < 4; ++i) {
        #pragma unroll
        for (int j = 0; j < 4; ++j) {
            #pragma unroll
            for (int r = 0; r < 4; ++r) {
                const int ql = wr * 64 + i * 16 + rowb + r;
                const int kl = wc * 64 + j * 16 + col;
                const float dist = qsq_r[i][r] + fmaf(-2.f, acc[i][j][r], ksq4[j]);
                Ds[(size_t)(qbase + ql) * SAMPLES + st * 128 + kl] = dist;
            }
        }
    }
}

// ================================================================ tau phase B: per-query rank-8 radix select (4 q/block)
__global__ __launch_bounds__(256)
void tau_select_kernel(const float* __restrict__ Ds, float* __restrict__ tau0, int rank) {
    __shared__ float D[4][SAMPLES];     // 32 KB
    const int q0 = blockIdx.x * 4, tid = threadIdx.x;
    {
        const float4* srcv = (const float4*)(Ds + (size_t)q0 * SAMPLES);
        float4* dstv = (float4*)&D[0][0];
        for (int i = tid; i < SAMPLES; i += 256) dstv[i] = srcv[i];
    }
    __syncthreads();

    const int wave = tid >> 6, lane = tid & 63;
    const float* Dq = D[wave];
    unsigned int v = 0;
    for (int bit = 30; bit >= 0; bit--) {
        const unsigned int tbits = v | (1u << bit);
        const float tf = __uint_as_float(tbits);
        unsigned int lc = 0;
        for (int i = lane; i < SAMPLES; i += 64) lc += (Dq[i] < tf) ? 1u : 0u;
        #pragma unroll
        for (int m = 1; m < 64; m <<= 1) lc += __shfl_xor(lc, m);
        if (lc < (unsigned)rank) v = tbits;
    }
    if (lane == 0) tau0[q0 + wave] = __uint_as_float(v);
}

// ================================================================ f16 MFMA distance GEMM + filter
// BARRIER-FREE: K fragments read direct global->register (L2-hot, 8x shared
// per XCD). No LDS staging, no per-tile sync; waves free-run with TLP.
__global__ __launch_bounds__(256)
void mfma_filter_kernel(const ushort* __restrict__ Qf, const ushort* __restrict__ Kf,
                        const float* __restrict__ ksq_g, const float* __restrict__ qsq_g,
                        const float* __restrict__ tau_g,
                        uint2* __restrict__ cand2, unsigned int* __restrict__ cnt2,
                        uint2* __restrict__ ovf, unsigned int* __restrict__ ovf_cnt) {
    __shared__ uint2 hitbuf[128][SEG];    // 20 KB block-local hits (mm_bits, kg)
    __shared__ unsigned int lcnt[128];    // per-query hit counts

    const int wg = blockIdx.x;
    const int qt = wg / NSTRIP;
    const int strip = wg - qt * NSTRIP;   // 96%8==0 -> wg%8 == strip%8 -> same XCD for all 8 qt
    int t0, len;
    if (strip < STRIP_R) { t0 = strip * 33; len = 33; }
    else { t0 = STRIP_R * 33 + (strip - STRIP_R) * 32; len = 32; }

    const int qbase = qt * 128;
    const int tid = threadIdx.x, lane = tid & 63, wave = tid >> 6;
    const int wr = wave >> 1, wc = wave & 1;   // wave covers 64q x 32k
    const int col = lane & 15, rowb = (lane >> 4) * 4;

    // Q fragments -> registers
    f16x8 af[4][4];
    {
        const ushort* qsrc = Qf + (size_t)qt * 16384 + lane * 8;
        #pragma unroll
        for (int i = 0; i < 4; ++i)
            #pragma unroll
            for (int s = 0; s < 4; ++s)
                af[i][s] = *(const f16x8*)(qsrc + ((wr * 4 + i) * 4 + s) * 512);
    }
    // per-lane thresholds only (qsq added at write-out)
    float thr_r[4][4];
    #pragma unroll
    for (int i = 0; i < 4; ++i)
        #pragma unroll
        for (int r = 0; r < 4; ++r) {
            const int qg = qbase + wr * 64 + i * 16 + rowb + r;
            thr_r[i][r] = tau_g[qg] + TSLACK - qsq_g[qg];
        }

    if (tid < 128) lcnt[tid] = 0u;
    __syncthreads();   // lcnt init visible (the only barrier before write-out)

    for (int t = 0; t < len; ++t) {
        const int kt = t0 + t;

        // K fragments: direct global->register, coalesced 1KB per load, L2-hot
        const ushort* ksrc = Kf + (size_t)kt * 8192 + lane * 8;
        f16x8 bfr[2][4];   // [j][s]
        #pragma unroll
        for (int j = 0; j < 2; ++j)
            #pragma unroll
            for (int s = 0; s < 4; ++s)
                bfr[j][s] = *(const f16x8*)(ksrc + ((wc * 2 + j) * 4 + s) * 512);

        float ksq2[2];
        ksq2[0] = ksq_g[kt * 64 + wc * 32 + col];
        ksq2[1] = ksq_g[kt * 64 + wc * 32 + 16 + col];

        f32x4 acc[4][2];
        #pragma unroll
        for (int i = 0; i < 4; ++i)
            #pragma unroll
            for (int j = 0; j < 2; ++j) acc[i][j] = (f32x4){0.f, 0.f, 0.f, 0.f};

        #pragma unroll
        for (int s = 0; s < 4; ++s)
            #pragma unroll
            for (int i = 0; i < 4; ++i)
                #pragma unroll
                for (int j = 0; j < 2; ++j)
                    acc[i][j] = __builtin_amdgcn_mfma_f32_16x16x32_f16(af[i][s], bfr[j][s], acc[i][j], 0, 0, 0);

        // epilogue: LDS-only hit append (no global traffic in the loop)
        #pragma unroll
        for (int i = 0; i < 4; ++i) {
            #pragma unroll
            for (int j = 0; j < 2; ++j) {
                #pragma unroll
                for (int r = 0; r < 4; ++r) {
                    const float mm = fmaf(-2.f, acc[i][j][r], ksq2[j]);
                    if (mm < thr_r[i][r]) {
                        const int ql = wr * 64 + i * 16 + rowb + r;
                        const unsigned kg = (unsigned)(kt * 64 + wc * 32 + j * 16 + col);
                        const unsigned slot = atomicAdd(&lcnt[ql], 1u);
                        if (slot < (unsigned)SEG) {
                            hitbuf[ql][slot] = make_uint2(__float_as_uint(mm), kg);
                        } else {   // rare overflow -> global list (dist computed here)
                            const int qg = qbase + ql;
                            const float dist = qsq_g[qg] + mm;
                            const unsigned op = atomicAdd(ovf_cnt, 1u);
                            if (op < (unsigned)OVFCAP)
                                ovf[op] = make_uint2(__float_as_uint(dist),
                                                     ((unsigned)qg << 18) | kg);
                        }
                    }
                }
            }
        }
    }
    __syncthreads();   // all epilogue hits visible before write-out

    // coalesced write-out: 2 threads per query
    {
        const int ql = tid >> 1, sub = tid & 1;
        const unsigned n = min(lcnt[ql], (unsigned)SEG);
        const float qsq = qsq_g[qbase + ql];
        uint2* seg = cand2 + ((size_t)strip * N_Q + qbase + ql) * SEG;
        for (unsigned i = sub; i < n; i += 2) {
            const uint2 e = hitbuf[ql][i];
            seg[i] = make_uint2(__float_as_uint(qsq + __uint_as_float(e.x)), e.y);
        }
        if (sub == 0) cnt2[(size_t)strip * N_Q + qbase + ql] = n;
    }
}

// ================================================================ select: gather -> radix a50 -> band-only exact recompute -> IDW
__global__ __launch_bounds__(256)
void select_kernel(const uint2* __restrict__ cand2, const unsigned int* __restrict__ cnt2,
                   const uint2* __restrict__ ovf, const unsigned int* __restrict__ ovf_cnt,
                   const float* __restrict__ keys, const float* __restrict__ qry,
                   const float* __restrict__ ksq_g, const float* __restrict__ qsq_g,
                   const float* __restrict__ values, float* __restrict__ out) {
    __shared__ float Qs[DIM];
    __shared__ unsigned dbits[CAP2];
    __shared__ unsigned didx[CAP2];
    __shared__ unsigned band_idx[128];
    __shared__ ull bandkey[128];
    __shared__ ull sel[64];
    __shared__ float vv[64];
    __shared__ unsigned int ns_sure, nb, galloc, a50_s;
    const int q = blockIdx.x, tid = threadIdx.x;

    if (tid < 32) ((float4*)Qs)[tid] = ((const float4*)(qry + (size_t)q * DIM))[tid];
    if (tid == 0) { ns_sure = 0; nb = 0; galloc = 0; }
    __syncthreads();

    // gather 96 segments: 2 threads/strip, LDS-atomic allocation (order-independent use)
    {
        const int s = tid >> 1, sub = tid & 1;
        if (s < NSTRIP) {
            const unsigned n = cnt2[(size_t)s * N_Q + q];
            unsigned base = 0;
            if (sub == 0) base = atomicAdd(&galloc, n);
            base = __shfl(base, (tid & 63) & ~1);
            const uint2* seg = cand2 + ((size_t)s * N_Q + q) * SEG;
            for (unsigned i = sub; i < n; i += 2) {
                const unsigned dsti = base + i;
                if (dsti < (unsigned)CAP2) {
                    const uint2 e = seg[i];
                    dbits[dsti] = e.x; didx[dsti] = e.y;
                }
            }
        }
    }
    // rare overflow entries
    {
        const unsigned no = min(*ovf_cnt, (unsigned)OVFCAP);
        for (unsigned i = tid; i < no; i += 256) {
            const uint2 e = ovf[i];
            if ((e.y >> 18) == (unsigned)q) {
                const unsigned dsti = atomicAdd(&galloc, 1u);
                if (dsti < (unsigned)CAP2) { dbits[dsti] = e.x; didx[dsti] = e.y & 0x3FFFFu; }
            }
        }
    }
    __syncthreads();
    const int c = min((int)galloc, CAP2);
    const int ksel = min(KNN, c);
    if (ksel == 0) { if (tid == 0) out[q] = 0.f; return; }

    // ---- radix select a50 = ksel-th smallest approx dist (wave-redundant, barrier-free)
    const int lane = tid & 63;
    {
        unsigned v = 0;
        for (int bit = 30; bit >= 0; bit--) {
            const unsigned tb = v | (1u << bit);
            unsigned lc = 0;
            for (int i = lane; i < c; i += 64) lc += (dbits[i] < tb) ? 1u : 0u;
            #pragma unroll
            for (int m = 1; m < 64; m <<= 1) lc += __shfl_xor(lc, m);
            if (lc < (unsigned)ksel) v = tb;
        }
        if (tid == 0) a50_s = v;
    }
    __syncthreads();
    const float a50 = __uint_as_float(a50_s);
    const float lo_cut = a50 - BANDW, hi_cut = a50 + BANDW;

    // ---- classify: sure (approx) / band (needs exact)
    for (int i = tid; i < c; i += 256) {
        const float A = __uint_as_float(dbits[i]);
        if (A < lo_cut) {
            const unsigned p = atomicAdd(&ns_sure, 1u);
            if (p < 64u) sel[p] = ((ull)dbits[i] << 32) | didx[i];
        } else if (A <= hi_cut) {
            const unsigned p = atomicAdd(&nb, 1u);
            if (p < 128u) band_idx[p] = didx[i];
        }
    }
    __syncthreads();
    const int nsure = min((int)ns_sure, 64);
    const int nband = min((int)nb, 128);
    const int need = min(ksel - nsure, nband);

    // ---- exact fp32 recompute for band (4 threads / element)
    const float qsq = qsq_g[q];
    for (int base = 0; base < nband; base += 64) {
        const int j = base + (tid >> 2);
        if (j < nband) {
            const int part = tid & 3;
            const int kidx = (int)band_idx[j];
            const float* kr = keys + (size_t)kidx * DIM + part * 32;
            const float* qp = Qs + part * 32;
            float acc = 0.f;
            #pragma unroll
            for (int d4 = 0; d4 < 8; ++d4) {
                const float4 kv = ((const float4*)kr)[d4];
                const float4 qv = ((const float4*)qp)[d4];
                acc = fmaf(qv.x, kv.x, acc); acc = fmaf(qv.y, kv.y, acc);
                acc = fmaf(qv.z, kv.z, acc); acc = fmaf(qv.w, kv.w, acc);
            }
            acc += __shfl_xor(acc, 1);
            acc += __shfl_xor(acc, 2);
            if (part == 0) {
                const float mm = fmaf(-2.f, acc, ksq_g[kidx]);
                const float dist = qsq + mm;
                bandkey[j] = ((ull)__float_as_uint(dist) << 32) | (unsigned)kidx;
            }
        }
    }
    __syncthreads();

    // ---- rank-place best `need` band elements (deterministic slots)
    if (tid < nband) {
        const ull mykey = bandkey[tid];
        int rank = 0;
        for (int i = 0; i < nband; ++i) rank += (bandkey[i] < mykey) ? 1 : 0;
        if (rank < need) sel[nsure + rank] = mykey;
    }
    __syncthreads();
    const int nfinal = nsure + max(need, 0);

    if (tid == 0) {  // deterministic order: insertion sort ascending (dist, idx)
        for (int a = 1; a < nfinal; a++) {
            const ull xk = sel[a];
            int b = a - 1;
            while (b >= 0 && sel[b] > xk) { sel[b + 1] = sel[b]; b--; }
            sel[b + 1] = xk;
        }
    }
    __syncthreads();
    if (tid < nfinal) vv[tid] = values[(unsigned)(sel[tid] & 0xFFFFFFFFull)];
    __syncthreads();

    if (tid == 0) {
        const float d0 = fmaxf(__uint_as_float((unsigned)(sel[0] >> 32)), 0.f);
        float res;
        if (d0 == 0.f) {
            res = vv[0];
        } else {
            float S = 0.f;
            for (int i = 0; i < nfinal; i++) {
                const float di = fmaxf(__uint_as_float((unsigned)(sel[i] >> 32)), 0.f);
                S += 1.f / (di + DELTA);
            }
            float o = 0.f;
            for (int i = 0; i < nfinal; i++) {
                const float di = fmaxf(__uint_as_float((unsigned)(sel[i] >> 32)), 0.f);
                const float w = 1.f / (di + DELTA);
                o += (w / S) * vv[i];
            }
            res = o;
        }
        out[q] = res;
    }
}

// ================================================================ launcher
extern "C" void kernel_launch(void* const* d_in, const int* in_sizes, int n_in,
                              void* d_out, int out_size, void* d_ws, size_t ws_size,
                              hipStream_t stream) {
    const float* qry    = (const float*)d_in[0];   // [1024,128]
    const float* keys   = (const float*)d_in[1];   // [200000,128]
    const float* values = (const float*)d_in[2];   // [200000,1]
    float* out = (float*)d_out;
    char* ws = (char*)d_ws;

    const size_t KF_OFF   = 0;
    const size_t QF_OFF   = KF_OFF  + (size_t)NKP * DIM * 2;     // 51,216,384
    const size_t KSQ_OFF  = QF_OFF  + (size_t)N_Q * DIM * 2;     // +262,144
    const size_t QSQ_OFF  = KSQ_OFF + (size_t)NKP * 4;           // +800,256
    const size_t TAU_OFF  = QSQ_OFF + 4096;
    const size_t OVFC_OFF = TAU_OFF + 4096;
    const size_t OVF_OFF  = OVFC_OFF + 4096;
    const size_t CNT2_OFF = OVF_OFF + (size_t)OVFCAP * 8;        // +512 KB
    const size_t CAND2_OFF= CNT2_OFF + (size_t)NSTRIP * N_Q * 4; // +384 KB
    // cand2: 96*1024*20*8 = 15.7 MB. Ds (8 MB) aliases cand2 (disjoint liveness).

    ushort* Kf  = (ushort*)(ws + KF_OFF);
    ushort* Qf  = (ushort*)(ws + QF_OFF);
    float*  ksq = (float*)(ws + KSQ_OFF);
    float*  qsq = (float*)(ws + QSQ_OFF);
    float*  tau = (float*)(ws + TAU_OFF);
    unsigned int* ovf_cnt = (unsigned int*)(ws + OVFC_OFF);
    uint2*  ovf  = (uint2*)(ws + OVF_OFF);
    unsigned int* cnt2 = (unsigned int*)(ws + CNT2_OFF);
    uint2*  cand2 = (uint2*)(ws + CAND2_OFF);
    float*  Ds   = (float*)(ws + CAND2_OFF);

    const int PREP_BLOCKS = (int)((NKP / 16 + N_Q / 16 + 3) / 4);   // 3142

    hipLaunchKernelGGL(prep_kernel, dim3(PREP_BLOCKS), dim3(256), 0, stream,
                       qry, keys, Kf, Qf, ksq, qsq, ovf_cnt);
    hipLaunchKernelGGL(tau_dist_kernel, dim3(8 * NSTILE), dim3(256), 0, stream,
                       Qf, Kf, ksq, qsq, Ds);
    hipLaunchKernelGGL(tau_select_kernel, dim3(N_Q / 4), dim3(256), 0, stream,
                       Ds, tau, SAMPLE_RANK);
    hipLaunchKernelGGL(mfma_filter_kernel, dim3(8 * NSTRIP), dim3(256), 0, stream,
                       Qf, Kf, ksq, qsq, tau, cand2, cnt2, ovf, ovf_cnt);
    hipLaunchKernelGGL(select_kernel, dim3(N_Q), dim3(256), 0, stream,
                       cand2, cnt2, ovf, ovf_cnt, keys, qry, ksq, qsq, values, out);
}